// Round 1
// baseline (134.442 us; speedup 1.0000x reference)
//
#include <hip/hip_runtime.h>

#define GD    256   // G*D latent row stride
#define DIM   64
#define KCB   1024
#define KP    256   // codewords staged per phase
#define NPHASE 4
#define RPB   256   // rows per block
#define RPW   64    // rows per wave

typedef float floatx4 __attribute__((ext_vector_type(4)));
typedef __bf16 bf16x8 __attribute__((ext_vector_type(8)));
typedef unsigned int uint;

union ABu { bf16x8 v; __bf16 h[8]; uint4 u4; };

extern "C" __global__ void __launch_bounds__(256, 2)
vq_kernel(const float* __restrict__ latents, const float* __restrict__ cbg,
          float* __restrict__ out, float* __restrict__ loss)
{
    __shared__ __attribute__((aligned(16))) uint cb_lds[KP * 32]; // KP rows x 64 bf16, 16B-chunk XOR swizzle
    __shared__ float initv_lds[KP];
    __shared__ uint  keys_lds[RPB];
    __shared__ float xsq_lds[RPB];

    const int tid  = threadIdx.x;
    const int wave = tid >> 6;
    const int lane = tid & 63;
    const int l15  = lane & 15;
    const int quad = lane >> 4;

    const int g     = blockIdx.x >> 7;     // 128 blocks per group
    const int chunk = blockIdx.x & 127;
    const int wRow0 = chunk * RPB + wave * RPW;

    const float* __restrict__ cbgrp = cbg + (size_t)g * (KCB * DIM);

    // ---- load A fragments (64 rows/wave, bf16) + per-row x_sq (fp32) ----
    bf16x8 afrag[4][2];
    #pragma unroll
    for (int rt = 0; rt < 4; ++rt) {
        const int row = wRow0 + rt * 16 + l15;
        const float* src = latents + (size_t)row * GD + g * DIM + quad * 8;
        float xp = 0.f;
        #pragma unroll
        for (int ks = 0; ks < 2; ++ks) {
            float4 f0 = *(const float4*)(src + ks * 32);
            float4 f1 = *(const float4*)(src + ks * 32 + 4);
            xp += f0.x*f0.x + f0.y*f0.y + f0.z*f0.z + f0.w*f0.w
                + f1.x*f1.x + f1.y*f1.y + f1.z*f1.z + f1.w*f1.w;
            ABu a;
            a.h[0] = (__bf16)f0.x; a.h[1] = (__bf16)f0.y;
            a.h[2] = (__bf16)f0.z; a.h[3] = (__bf16)f0.w;
            a.h[4] = (__bf16)f1.x; a.h[5] = (__bf16)f1.y;
            a.h[6] = (__bf16)f1.z; a.h[7] = (__bf16)f1.w;
            afrag[rt][ks] = a.v;
        }
        xp += __shfl_xor(xp, 16);
        xp += __shfl_xor(xp, 32);
        if (quad == 0) xsq_lds[wave * RPW + rt * 16 + l15] = xp;
    }

    uint best[4][4];
    #pragma unroll
    for (int rt = 0; rt < 4; ++rt)
        #pragma unroll
        for (int r = 0; r < 4; ++r) best[rt][r] = 0xFFFFFFFFu;

    for (int p = 0; p < NPHASE; ++p) {
        __syncthreads();   // previous phase's LDS reads complete
        // ---- stage 256 codewords fp32->bf16 into LDS, compute -csq/2-0.5 ----
        {
            const int kk = tid;  // BLOCK == KP
            const float* src = cbgrp + (size_t)(p * KP + kk) * DIM;
            float csq = 0.f;
            #pragma unroll
            for (int c = 0; c < 8; ++c) {
                float4 f0 = *(const float4*)(src + c * 8);
                float4 f1 = *(const float4*)(src + c * 8 + 4);
                csq += f0.x*f0.x + f0.y*f0.y + f0.z*f0.z + f0.w*f0.w
                     + f1.x*f1.x + f1.y*f1.y + f1.z*f1.z + f1.w*f1.w;
                ABu t;
                t.h[0] = (__bf16)f0.x; t.h[1] = (__bf16)f0.y;
                t.h[2] = (__bf16)f0.z; t.h[3] = (__bf16)f0.w;
                t.h[4] = (__bf16)f1.x; t.h[5] = (__bf16)f1.y;
                t.h[6] = (__bf16)f1.z; t.h[7] = (__bf16)f1.w;
                const int dc = c ^ (kk & 7);
                *(uint4*)&cb_lds[kk * 32 + dc * 4] = t.u4;
            }
            initv_lds[kk] = -0.5f * csq - 0.5f;   // makes all scores < 0
        }
        __syncthreads();

        const int pbase = p * KP;
        #pragma unroll 2
        for (int t = 0; t < 16; ++t) {
            const int kkl = t * 16 + l15;       // local codeword this lane scores
            const float v = initv_lds[kkl];
            ABu b0, b1;
            b0.u4 = *(const uint4*)&cb_lds[kkl * 32 + (((quad    ) ^ (kkl & 7)) << 2)];
            b1.u4 = *(const uint4*)&cb_lds[kkl * 32 + (((quad + 4) ^ (kkl & 7)) << 2)];
            const uint kcol = (uint)(pbase + kkl);
            #pragma unroll
            for (int rt = 0; rt < 4; ++rt) {
                floatx4 acc = { v, v, v, v };
                acc = __builtin_amdgcn_mfma_f32_16x16x32_bf16(afrag[rt][0], b0.v, acc, 0, 0, 0);
                acc = __builtin_amdgcn_mfma_f32_16x16x32_bf16(afrag[rt][1], b1.v, acc, 0, 0, 0);
                // score = x.c - csq/2 - 0.5 < 0 always -> raw bits are monotone
                // (more negative = larger uint). Pack idx in low 10 bits, min_u32.
                #pragma unroll
                for (int r = 0; r < 4; ++r) {
                    const uint key = (__float_as_uint(acc[r]) & 0xFFFFFC00u) | kcol;
                    best[rt][r] = best[rt][r] < key ? best[rt][r] : key;
                }
            }
        }
    }

    // ---- reduce argmin keys across the 16 column lanes of each row ----
    #pragma unroll
    for (int rt = 0; rt < 4; ++rt) {
        #pragma unroll
        for (int r = 0; r < 4; ++r) {
            uint kmin = best[rt][r];
            #pragma unroll
            for (int m = 1; m <= 8; m <<= 1) {
                const uint o = (uint)__shfl_xor((int)kmin, m);
                kmin = o < kmin ? o : kmin;
            }
            if (l15 == 0) keys_lds[wave * RPW + rt * 16 + quad * 4 + r] = kmin;
        }
    }
    __syncthreads();

    // ---- gather fp32 codewords, write output, accumulate loss ----
    const float4* __restrict__ cb4 = (const float4*)cbgrp;
    float4* __restrict__ out4 = (float4*)out;
    float lsum = 0.f;
    #pragma unroll 4
    for (int i = 0; i < 16; ++i) {
        const int r = i * 4 + quad;                 // 4 rows per iter, 16 lanes each
        const uint key = keys_lds[wave * RPW + r];
        const int kidx = (int)(key & 1023u);
        const int row = wRow0 + r;
        const float4 cw = cb4[(size_t)kidx * 16 + l15];
        out4[(size_t)row * 64 + g * 16 + l15] = cw;
        if (l15 == 0) {
            // dist = x_sq - 2*s + c_sq = x_sq - 2*score - 1
            const float sc = __uint_as_float(key & 0xFFFFFC00u);
            lsum += xsq_lds[wave * RPW + r] - 2.f * sc - 1.f;
        }
    }
    #pragma unroll
    for (int m = 1; m <= 32; m <<= 1) lsum += __shfl_xor(lsum, m);
    if (lane == 0) atomicAdd(loss, lsum * (1.25f / 8388608.0f));
}

extern "C" void kernel_launch(void* const* d_in, const int* in_sizes, int n_in,
                              void* d_out, int out_size, void* d_ws, size_t ws_size,
                              hipStream_t stream)
{
    const float* latents = (const float*)d_in[0];
    const float* cbg     = (const float*)d_in[1];
    float* out  = (float*)d_out;
    float* lossp = out + 8388608;           // quantized [8*4096*256] then scalar loss
    hipMemsetAsync(lossp, 0, sizeof(float), stream);
    vq_kernel<<<dim3(512), dim3(256), 0, stream>>>(latents, cbg, out, lossp);
}